// Round 10
// baseline (895.346 us; speedup 1.0000x reference)
//
#include <hip/hip_runtime.h>
#include <math.h>

#define BB 2
#define LL 2048
#define DD 1024
#define HH 16
#define SCALE 0.03125f   // 1/sqrt(1024)

#define ATTN_ELEMS ((size_t)BB * LL * DD)           // 4,194,304 fp32

typedef unsigned short u16;
typedef __attribute__((ext_vector_type(8))) short bf16x8;
typedef __attribute__((ext_vector_type(4))) float f32x4;

// fp32 -> bf16 bits, round-to-nearest-even
__device__ __forceinline__ short f2bf_rne(float f) {
    union { float f; unsigned u; } c; c.f = f;
    unsigned u = c.u;
    u += 0x7fffu + ((u >> 16) & 1u);
    return (short)(u >> 16);
}

// Branchless stable insert of (cv,ci) into descending-sorted 8-list.
// Precondition: cv > tv[7]. Candidates arrive in ascending index order.
__device__ __forceinline__ void insert8(float (&tv)[8], int (&ti)[8], float cv, int ci) {
    bool g0 = cv > tv[0], g1 = cv > tv[1], g2 = cv > tv[2], g3 = cv > tv[3],
         g4 = cv > tv[4], g5 = cv > tv[5], g6 = cv > tv[6];
    tv[7] = g6 ? tv[6] : cv;                 ti[7] = g6 ? ti[6] : ci;
    tv[6] = g5 ? tv[5] : (g6 ? cv : tv[6]);  ti[6] = g5 ? ti[5] : (g6 ? ci : ti[6]);
    tv[5] = g4 ? tv[4] : (g5 ? cv : tv[5]);  ti[5] = g4 ? ti[4] : (g5 ? ci : ti[5]);
    tv[4] = g3 ? tv[3] : (g4 ? cv : tv[4]);  ti[4] = g3 ? ti[3] : (g4 ? ci : ti[4]);
    tv[3] = g2 ? tv[2] : (g3 ? cv : tv[3]);  ti[3] = g2 ? ti[2] : (g3 ? ci : ti[3]);
    tv[2] = g1 ? tv[1] : (g2 ? cv : tv[2]);  ti[2] = g1 ? ti[1] : (g2 ? ci : ti[2]);
    tv[1] = g0 ? tv[0] : (g1 ? cv : tv[1]);  ti[1] = g0 ? ti[0] : (g1 ? ci : ti[1]);
    tv[0] = g0 ? cv : tv[0];                 ti[0] = g0 ? ci : ti[0];
}

// Merge four descending-sorted 8-lists -> top-8 (value desc, index asc on ties).
__device__ __forceinline__ void merge4(
    const float* v0, const int* i0, const float* v1, const int* i1,
    const float* v2, const int* i2, const float* v3, const int* i3,
    float* ov, int* oi)
{
    int p0 = 0, p1 = 0, p2 = 0, p3 = 0;
    #pragma unroll
    for (int s = 0; s < 8; ++s) {
        float a0 = v0[p0], a1 = v1[p1], a2 = v2[p2], a3 = v3[p3];
        int   b0 = i0[p0], b1 = i1[p1], b2 = i2[p2], b3 = i3[p3];
        float bv = a0; int bi = b0; int bc = 0;
        if (a1 > bv || (a1 == bv && b1 < bi)) { bv = a1; bi = b1; bc = 1; }
        if (a2 > bv || (a2 == bv && b2 < bi)) { bv = a2; bi = b2; bc = 2; }
        if (a3 > bv || (a3 == bv && b3 < bi)) { bv = a3; bi = b3; bc = 3; }
        p0 += (bc == 0); p1 += (bc == 1); p2 += (bc == 2); p3 += (bc == 3);
        ov[s] = bv; oi[s] = bi;
    }
}

// ---------------------------------------------------------------------------
// Fused attention: one block per (b, h, 64-query tile). 256 threads = 4 waves.
// RNE-bf16 MFMA scores select top-12 candidates/row (provably containing the
// exact top-8); candidates rescored in exact sequential fp32; then top-8 +
// softmax + scatter + context. K staged in 256-col tiles, fragment order with
// XOR bank swizzle (writes and reads both <=2-way => conflict-free).
__global__ __launch_bounds__(256) void attn_kernel(
    const float* __restrict__ q, const float* __restrict__ k, const float* __restrict__ v,
    float* __restrict__ aw, float* __restrict__ ctx)
{
    const int bid  = blockIdx.x;
    const int qt   = bid & 31;
    const int h    = (bid >> 5) & 15;
    const int b    = bid >> 9;
    const int t    = threadIdx.x;
    const int wv   = t >> 6;
    const int lane = t & 63;
    const int li   = lane & 15;
    const int quad = lane >> 4;

    __shared__ __align__(16) u16 khi[16384];   // 32 KB; aliased as mv/mi in merge
    __shared__ float s2v[32][4][8];
    __shared__ int   s2i[32][4][8];
    __shared__ int   cidx[32][12];
    __shared__ float cs[32][12];
    __shared__ float wrow[64][8];
    __shared__ int   wix[64][8];

    const float* kbase = k + ((size_t)b * LL) * DD + h * 64;
    f32x4* awz = (f32x4*)(aw + (((size_t)(b * HH + h) * LL) + (size_t)qt * 64) * LL);
    const f32x4 zero4 = {0.f, 0.f, 0.f, 0.f};

    // Q fragments (A operand), rows qt*64 + wv*16 + li, RNE bf16
    bf16x8 qh0, qh1;
    {
        const float* qrow = q + ((size_t)(b * LL + qt * 64 + wv * 16 + li)) * DD + h * 64;
        float x[8];
        *(f32x4*)x       = *(const f32x4*)(qrow + quad * 8);
        *(f32x4*)(x + 4) = *(const f32x4*)(qrow + quad * 8 + 4);
        #pragma unroll
        for (int e = 0; e < 8; ++e) qh0[e] = f2bf_rne(x[e]);
        *(f32x4*)x       = *(const f32x4*)(qrow + 32 + quad * 8);
        *(f32x4*)(x + 4) = *(const f32x4*)(qrow + 32 + quad * 8 + 4);
        #pragma unroll
        for (int e = 0; e < 8; ++e) qh1[e] = f2bf_rne(x[e]);
    }

    float tv[4][8]; int tix[4][8];
    #pragma unroll
    for (int r = 0; r < 4; ++r)
        #pragma unroll
        for (int s = 0; s < 8; ++s) { tv[r][s] = -INFINITY; tix[r][s] = 0; }

    const int quad2 = quad * 2;
    for (int iter = 0; iter < 8; ++iter) {
        __syncthreads();                       // prior tile's frag reads done
        // stage+convert K tile: 256 cols x 64 dims, swizzled fragment order
        #pragma unroll
        for (int j = 0; j < 8; ++j) {
            int f   = j * 256 + t;             // 0..2047
            int col = f >> 3;                  // 0..255
            int c   = (f >> 2) & 1;            // k32 chunk
            int qd  = f & 3;                   // quad
            const float* src = kbase + (size_t)(iter * 256 + col) * DD + c * 32 + qd * 8;
            float x[8];
            *(f32x4*)x       = *(const f32x4*)src;
            *(f32x4*)(x + 4) = *(const f32x4*)(src + 4);
            bf16x8 h8;
            #pragma unroll
            for (int e = 0; e < 8; ++e) h8[e] = f2bf_rne(x[e]);
            int beta  = (col >> 4) * 2 + c;
            int chunk = ((qd << 4) + (col & 15)) ^ (qd * 2 + c);
            *(bf16x8*)&khi[(beta << 9) + (chunk << 3)] = h8;
        }
        // fused aw zero-fill: 16 float4 per thread per iter (block's 64 rows)
        #pragma unroll
        for (int i = 0; i < 16; ++i) awz[iter * 4096 + i * 256 + t] = zero4;
        __syncthreads();

        #pragma unroll
        for (int s = 0; s < 16; ++s) {
            int fo = s << 10;
            bf16x8 kh0 = *(bf16x8*)&khi[fo + ((lane ^ quad2) << 3)];
            bf16x8 kh1 = *(bf16x8*)&khi[fo + 512 + ((lane ^ (quad2 + 1)) << 3)];
            f32x4 c4 = {0.f, 0.f, 0.f, 0.f};
            c4 = __builtin_amdgcn_mfma_f32_16x16x32_bf16(qh0, kh0, c4, 0, 0, 0);
            c4 = __builtin_amdgcn_mfma_f32_16x16x32_bf16(qh1, kh1, c4, 0, 0, 0);
            int ci = iter * 256 + s * 16 + li;
            #pragma unroll
            for (int r = 0; r < 4; ++r) {
                float cv = c4[r] * SCALE;
                if (cv > tv[r][7]) insert8(tv[r], tix[r], cv, ci);
            }
        }
    }

    // merge phase: 2 batches of 32 rows; mv/mi alias the K staging area
    float* mv = (float*)khi;
    int*   mi = (int*)(khi + 8192);
    for (int bb = 0; bb < 2; ++bb) {
        __syncthreads();
        if ((wv >> 1) == bb) {
            int rl0 = (wv & 1) * 16 + quad * 4;
            #pragma unroll
            for (int r = 0; r < 4; ++r) {
                int base = (rl0 + r) * 128 + li * 8;
                #pragma unroll
                for (int s = 0; s < 8; ++s) { mv[base + s] = tv[r][s]; mi[base + s] = tix[r][s]; }
            }
        }
        __syncthreads();
        // stage 1: 128 threads: 4-way merge of 4 streams -> top-8 each
        if (t < 128) {
            int rr = t >> 2, p = t & 3;
            int base = rr * 128 + p * 32;
            merge4(&mv[base], &mi[base], &mv[base + 8], &mi[base + 8],
                   &mv[base + 16], &mi[base + 16], &mv[base + 24], &mi[base + 24],
                   s2v[rr][p], s2i[rr][p]);
        }
        __syncthreads();
        // stage 2: MFMA top-12 candidate indices per row
        if (t < 32) {
            int rr = t;
            int pp[4] = {0, 0, 0, 0};
            #pragma unroll
            for (int s = 0; s < 12; ++s) {
                float bv = -INFINITY; int bi = 0x7fffffff; int bc = 0;
                #pragma unroll
                for (int l = 0; l < 4; ++l) {
                    if (pp[l] < 8) {
                        float hv = s2v[rr][l][pp[l]]; int hi2 = s2i[rr][l][pp[l]];
                        if (hv > bv || (hv == bv && hi2 < bi)) { bv = hv; bi = hi2; bc = l; }
                    }
                }
                pp[bc] += 1;
                cidx[rr][s] = bi;
            }
        }
        __syncthreads();
        // rescore the 12 candidates per row in exact sequential fp32
        for (int task = t; task < 384; task += 256) {
            int row = task / 12, c = task - row * 12;
            const float* qp = q + ((size_t)(b * LL + qt * 64 + bb * 32 + row)) * DD + h * 64;
            const float* kp = k + ((size_t)(b * LL + cidx[row][c])) * DD + h * 64;
            float acc = 0.f;
            for (int d4 = 0; d4 < 16; ++d4) {
                f32x4 qa = *(const f32x4*)(qp + d4 * 4);
                f32x4 ka = *(const f32x4*)(kp + d4 * 4);
                acc = fmaf(qa[0], ka[0], acc);
                acc = fmaf(qa[1], ka[1], acc);
                acc = fmaf(qa[2], ka[2], acc);
                acc = fmaf(qa[3], ka[3], acc);
            }
            cs[row][c] = acc * SCALE;
        }
        __syncthreads();
        // final top-8 (fp32 desc, index asc), softmax, scatter
        if (t < 32) {
            int rr = t;
            float vv[12]; int ii[12];
            #pragma unroll
            for (int c = 0; c < 12; ++c) { vv[c] = cs[rr][c]; ii[c] = cidx[rr][c]; }
            float fv[8]; int fi[8];
            #pragma unroll
            for (int s = 0; s < 8; ++s) {
                float bv = -INFINITY; int bi = 0x7fffffff; int bc = 0;
                #pragma unroll
                for (int c = 0; c < 12; ++c) {
                    if (vv[c] > bv || (vv[c] == bv && ii[c] < bi)) { bv = vv[c]; bi = ii[c]; bc = c; }
                }
                vv[bc] = -INFINITY;
                fv[s] = bv; fi[s] = bi;
            }
            float m = fv[0];
            float e0[8]; float sum = 0.f;
            #pragma unroll
            for (int s = 0; s < 8; ++s) { e0[s] = __expf(fv[s] - m); sum += e0[s]; }
            float inv = 1.0f / sum;
            int grow = bb * 32 + rr;
            float* awrow = aw + (((size_t)(b * HH + h) * LL) + (size_t)qt * 64 + grow) * LL;
            #pragma unroll
            for (int s = 0; s < 8; ++s) {
                float w8 = e0[s] * inv;
                awrow[fi[s]] = w8;
                wrow[grow][s] = w8; wix[grow][s] = fi[s];
            }
        }
    }
    __syncthreads();

    // context: 64 rows x 16 f32x4-segments, 4 per thread
    const float* vbase = v + ((size_t)b * LL) * DD + h * 64;
    #pragma unroll
    for (int i = 0; i < 4; ++i) {
        int id = i * 256 + t;
        int row = id >> 4, seg = id & 15;
        f32x4 acc = {0.f, 0.f, 0.f, 0.f};
        #pragma unroll
        for (int s = 0; s < 8; ++s) {
            float ws = wrow[row][s];
            f32x4 vvv = *(const f32x4*)(vbase + (size_t)wix[row][s] * DD + seg * 4);
            acc[0] = fmaf(ws, vvv[0], acc[0]);
            acc[1] = fmaf(ws, vvv[1], acc[1]);
            acc[2] = fmaf(ws, vvv[2], acc[2]);
            acc[3] = fmaf(ws, vvv[3], acc[3]);
        }
        *(f32x4*)(ctx + ((size_t)(b * LL + qt * 64 + row)) * DD + h * 64 + seg * 4) = acc;
    }
}

// ---------------------------------------------------------------------------
// Projection, workspace path (NO aliasing). RNE-bf16 MFMA (err ~7e-4 << thr).
__global__ __launch_bounds__(256) void linear_ws_kernel(
    const float* __restrict__ ctx, const float* __restrict__ w,
    const float* __restrict__ bias, float* __restrict__ out)
{
    const int bid  = blockIdx.x;
    const int nb   = bid & 15, mb = bid >> 4;
    const int t    = threadIdx.x;
    const int wv   = t >> 6;
    const int lane = t & 63;
    const int li   = lane & 15;
    const int quad = lane >> 4;

    __shared__ u16 bhi[8192];   // 16 KB

    f32x4 acc0 = {0.f,0.f,0.f,0.f}, acc1 = {0.f,0.f,0.f,0.f},
          acc2 = {0.f,0.f,0.f,0.f}, acc3 = {0.f,0.f,0.f,0.f};
    const float* arow = ctx + (size_t)(mb * 64 + wv * 16 + li) * DD;

    for (int kc = 0; kc < 8; ++kc) {
        __syncthreads();
        #pragma unroll
        for (int j = 0; j < 4; ++j) {
            int f   = j * 256 + t;
            int col = f >> 4;                  // 0..63
            int c   = (f >> 2) & 3;            // k32 sub-chunk
            int qd  = f & 3;
            const float* src = w + (size_t)(nb * 64 + col) * DD + kc * 128 + c * 32 + qd * 8;
            float x[8];
            *(f32x4*)x       = *(const f32x4*)src;
            *(f32x4*)(x + 4) = *(const f32x4*)(src + 4);
            bf16x8 h8;
            #pragma unroll
            for (int e = 0; e < 8; ++e) h8[e] = f2bf_rne(x[e]);
            int beta  = (col >> 4) * 4 + c;
            int chunk = ((qd << 4) + (col & 15)) ^ (qd * 2 + c);
            *(bf16x8*)&bhi[(beta << 9) + (chunk << 3)] = h8;
        }
        __syncthreads();

        bf16x8 ah[4];
        #pragma unroll
        for (int c = 0; c < 4; ++c) {
            float x[8];
            *(f32x4*)x       = *(const f32x4*)(arow + kc * 128 + c * 32 + quad * 8);
            *(f32x4*)(x + 4) = *(const f32x4*)(arow + kc * 128 + c * 32 + quad * 8 + 4);
            #pragma unroll
            for (int e = 0; e < 8; ++e) ah[c][e] = f2bf_rne(x[e]);
        }
        #pragma unroll
        for (int c = 0; c < 4; ++c) {
            int cread = (lane ^ (quad * 2 + c)) << 3;
            bf16x8 bh0 = *(bf16x8*)&bhi[(( 0 + c) << 9) + cread];
            bf16x8 bh1 = *(bf16x8*)&bhi[(( 4 + c) << 9) + cread];
            bf16x8 bh2 = *(bf16x8*)&bhi[(( 8 + c) << 9) + cread];
            bf16x8 bh3 = *(bf16x8*)&bhi[((12 + c) << 9) + cread];
            acc0 = __builtin_amdgcn_mfma_f32_16x16x32_bf16(ah[c], bh0, acc0, 0, 0, 0);
            acc1 = __builtin_amdgcn_mfma_f32_16x16x32_bf16(ah[c], bh1, acc1, 0, 0, 0);
            acc2 = __builtin_amdgcn_mfma_f32_16x16x32_bf16(ah[c], bh2, acc2, 0, 0, 0);
            acc3 = __builtin_amdgcn_mfma_f32_16x16x32_bf16(ah[c], bh3, acc3, 0, 0, 0);
        }
    }

    #pragma unroll
    for (int st = 0; st < 4; ++st) {
        f32x4 a = (st == 0) ? acc0 : (st == 1) ? acc1 : (st == 2) ? acc2 : acc3;
        int col = nb * 64 + st * 16 + li;
        float bb2 = bias[col];
        #pragma unroll
        for (int r = 0; r < 4; ++r)
            out[(size_t)(mb * 64 + wv * 16 + quad * 4 + r) * DD + col] = a[r] + bb2;
    }
}

// ---------------------------------------------------------------------------
// Projection, in-place fallback. Each block owns 16 rows exclusively, stages
// them to LDS BEFORE any write, computes the rows' full 1024 output cols.
__global__ __launch_bounds__(256) void linear_inplace_kernel(
    float* io, const float* __restrict__ w, const float* __restrict__ bias)
{
    __shared__ u16 ahi[16384];   // 32 KB
    const int t    = threadIdx.x;
    const int m0   = blockIdx.x * 16;
    const int wv   = t >> 6;
    const int lane = t & 63;
    const int li   = lane & 15;
    const int quad = lane >> 4;

    #pragma unroll
    for (int i = 0; i < 8; ++i) {
        int id  = i * 256 + t;
        int row = id >> 7;            // 0..15
        int c   = (id >> 2) & 31;     // k32 chunk
        int qd  = id & 3;
        const float* src = io + (size_t)(m0 + row) * DD + c * 32 + qd * 8;
        float x[8];
        *(f32x4*)x       = *(const f32x4*)src;
        *(f32x4*)(x + 4) = *(const f32x4*)(src + 4);
        bf16x8 h8;
        #pragma unroll
        for (int e = 0; e < 8; ++e) h8[e] = f2bf_rne(x[e]);
        int chunk = ((qd << 4) + row) ^ ((qd * 2 + c) & 7);
        *(bf16x8*)&ahi[(c << 9) + (chunk << 3)] = h8;
    }
    __syncthreads();

    f32x4 acc[16];
    #pragma unroll
    for (int i = 0; i < 16; ++i) acc[i] = (f32x4){0.f, 0.f, 0.f, 0.f};

    for (int c = 0; c < 32; ++c) {
        bf16x8 ah = *(bf16x8*)&ahi[(c << 9) + ((lane ^ ((quad * 2 + c) & 7)) << 3)];
        #pragma unroll
        for (int sub = 0; sub < 16; ++sub) {
            int col = wv * 256 + sub * 16 + li;
            const float* src = w + (size_t)col * DD + c * 32 + quad * 8;
            float x[8];
            *(f32x4*)x       = *(const f32x4*)src;
            *(f32x4*)(x + 4) = *(const f32x4*)(src + 4);
            bf16x8 bh;
            #pragma unroll
            for (int e = 0; e < 8; ++e) bh[e] = f2bf_rne(x[e]);
            acc[sub] = __builtin_amdgcn_mfma_f32_16x16x32_bf16(ah, bh, acc[sub], 0, 0, 0);
        }
    }

    #pragma unroll
    for (int sub = 0; sub < 16; ++sub) {
        int col = wv * 256 + sub * 16 + li;
        float bb2 = bias[col];
        #pragma unroll
        for (int r = 0; r < 4; ++r)
            io[(size_t)(m0 + quad * 4 + r) * DD + col] = acc[sub][r] + bb2;
    }
}

extern "C" void kernel_launch(void* const* d_in, const int* in_sizes, int n_in,
                              void* d_out, int out_size, void* d_ws, size_t ws_size,
                              hipStream_t stream) {
    const float* q    = (const float*)d_in[0];
    const float* k    = (const float*)d_in[1];
    const float* v    = (const float*)d_in[2];
    const float* w    = (const float*)d_in[3];
    const float* bias = (const float*)d_in[4];

    float* out = (float*)d_out;                  // attn_out [B*L*D]
    float* aw  = out + ATTN_ELEMS;               // attn_weights [B*H*L*L]

    const bool use_ws = (d_ws != nullptr) && (ws_size >= ATTN_ELEMS * sizeof(float));
    float* ctx = use_ws ? (float*)d_ws : out;

    attn_kernel<<<BB * HH * (LL / 64), 256, 0, stream>>>(q, k, v, aw, ctx);
    if (use_ws) {
        linear_ws_kernel<<<(BB * LL / 64) * (DD / 64), 256, 0, stream>>>(ctx, w, bias, out);
    } else {
        linear_inplace_kernel<<<BB * LL / 16, 256, 0, stream>>>(out, w, bias);
    }
}